// Round 22
// baseline (114.439 us; speedup 1.0000x reference)
//
#include <hip/hip_runtime.h>

#define NEGV (-100000000.0f)
typedef __attribute__((ext_vector_type(2))) float f32x2;
typedef __attribute__((ext_vector_type(8))) short bf16x8;
typedef __attribute__((ext_vector_type(4))) float f32x4v;

constexpr int BB = 32, MM = 24, RR = 384, DD = 2048;
constexpr int EPITCH = 400;   // eT row pitch (bytes): 100 dwords = 4 mod 32 banks

// pack two f32 -> two bf16 (round half-up)
static __device__ __forceinline__ unsigned pk2bf(float a, float b) {
  unsigned au = __float_as_uint(a) + 0x8000u;
  unsigned bu = __float_as_uint(b) + 0x8000u;
  return (au >> 16) | (bu & 0xffff0000u);
}

// ---------------- Kernel A: cast+MFMA GEMM, 256 thr, depth-3 reg pipeline ---
__global__ __launch_bounds__(256) void kA(const float* __restrict__ region,
    const float* __restrict__ t0w, const float* __restrict__ t0b,
    const float* __restrict__ t1w, const float* __restrict__ t1b,
    float* __restrict__ h0h1) {
  __shared__ unsigned short Abuf[2][32 * 128];
  __shared__ unsigned short Bbuf[2][32 * 128];
  const int tid = threadIdx.x;
  const int row0 = blockIdx.x * 32;

  const int srow = tid >> 3;
  const int sq = tid & 7;
  const float* aSrc = region + (size_t)(row0 + srow) * DD + sq * 16;
  const float* bSrc = ((srow < 16) ? (t0w + (size_t)srow * DD)
                                   : (t1w + (size_t)(srow - 16) * DD)) + sq * 16;

  auto LOADS = [&](float4* s, int t) {
    const int d0 = t * 128;
#pragma unroll
    for (int i = 0; i < 4; ++i) s[i] = *(const float4*)(aSrc + d0 + i * 4);
#pragma unroll
    for (int i = 0; i < 4; ++i) s[4 + i] = *(const float4*)(bSrc + d0 + i * 4);
  };
  const int wbase = srow * 256 + sq * 32;
  const int wxor = (srow & 7) << 4;
  auto WRITES = [&](const float4* s, int buf) {
    unsigned char* Ab = (unsigned char*)&Abuf[buf][0];
    unsigned char* Bb = (unsigned char*)&Bbuf[buf][0];
#pragma unroll
    for (int i = 0; i < 2; ++i) {
      float4 x = s[i * 2], y = s[i * 2 + 1];
      uint4 pk;
      pk.x = pk2bf(x.x, x.y); pk.y = pk2bf(x.z, x.w);
      pk.z = pk2bf(y.x, y.y); pk.w = pk2bf(y.z, y.w);
      *(uint4*)(Ab + ((wbase + i * 16) ^ wxor)) = pk;
      float4 u = s[4 + i * 2], v = s[4 + i * 2 + 1];
      uint4 qk;
      qk.x = pk2bf(u.x, u.y); qk.y = pk2bf(u.z, u.w);
      qk.z = pk2bf(v.x, v.y); qk.w = pk2bf(v.z, v.w);
      *(uint4*)(Bb + ((wbase + i * 16) ^ wxor)) = qk;
    }
  };

  const int w = tid >> 6;
  const int rt = w & 1;
  const int ht = w >> 1;
  const int lane = tid & 63;
  const int arow = rt * 16 + (lane & 15);
  const int bh = lane & 15;
  const int brow = ht * 16 + bh;
  const int koff = (lane >> 4) * 8;
  const int axor = (arow & 7) << 4;
  const int bxor = (brow & 7) << 4;

  f32x4v acc = {0.f, 0.f, 0.f, 0.f};
  auto MFMAT = [&](int buf) {
    const unsigned char* Ab = (const unsigned char*)&Abuf[buf][0];
    const unsigned char* Bb = (const unsigned char*)&Bbuf[buf][0];
#pragma unroll
    for (int kk = 0; kk < 4; ++kk) {
      const int kb = (kk * 32 + koff) * 2;
      bf16x8 av = *(const bf16x8*)(Ab + ((arow * 256 + kb) ^ axor));
      bf16x8 bv = *(const bf16x8*)(Bb + ((brow * 256 + kb) ^ bxor));
      acc = __builtin_amdgcn_mfma_f32_16x16x32_bf16(av, bv, acc, 0, 0, 0);
    }
  };

  float4 sA[8], sB[8], sC[8];
  LOADS(sA, 0);
  WRITES(sA, 0);
  LOADS(sB, 1);
  LOADS(sC, 2);
  for (int t = 0; t < 16; t += 3) {
    __syncthreads();
    if (t + 1 < 16) WRITES(sB, (t + 1) & 1);
    if (t + 3 < 16) LOADS(sA, t + 3);
    MFMAT(t & 1);
    if (t + 1 < 16) {
      __syncthreads();
      if (t + 2 < 16) WRITES(sC, (t + 2) & 1);
      if (t + 4 < 16) LOADS(sB, t + 4);
      MFMAT((t + 1) & 1);
    }
    if (t + 2 < 16) {
      __syncthreads();
      if (t + 3 < 16) WRITES(sA, (t + 3) & 1);
      if (t + 5 < 16) LOADS(sC, t + 5);
      MFMAT(t & 1);
    }
  }

  const float bias = (ht == 0) ? t0b[bh] : t1b[bh];
#pragma unroll
  for (int i = 0; i < 4; ++i) {
    const int rg = row0 + rt * 16 + (lane >> 4) * 4 + i;
    h0h1[(size_t)rg * 32 + ht * 16 + bh] = acc[i] + bias;
  }
}

// ---------------- Kernel YT: r19-proven version (exact) ---------------------
// grid 256 = (b x 8 chunks of 48 rows). thread = (r 0..47, jq 0..7).
__global__ __launch_bounds__(384) void kYT(const float* __restrict__ h0h1,
    const float* __restrict__ trw, const float* __restrict__ trb,
    const float* __restrict__ gt, const float* __restrict__ aff,
    const int* __restrict__ nmen, const int* __restrict__ nreg,
    int* __restrict__ mlist, int* __restrict__ kcnt, float* __restrict__ Em,
    float* __restrict__ bilinP, unsigned char* __restrict__ expb,
    float* __restrict__ expTmax) {
  __shared__ float h1T[16][388];
  __shared__ float h0L[48][16];
  __shared__ float Tl[48][388];
  __shared__ float RP[MM][392];
  __shared__ float part[48][26];
  __shared__ float rsumL[MM], EmL[MM];
  __shared__ int mlistL[MM];
  __shared__ int kcntL;
  const int b = blockIdx.x & 31;
  const int chunk = blockIdx.x >> 5;
  const int r0 = chunk * 48;
  const int tid = threadIdx.x;
  const int lane = tid & 63;
  const int wv = tid >> 6;
  const int nm = nmen[b], nr = nreg[b];

  // ---- kCM prologue on 6 waves ----
  for (int m = wv; m < MM; m += 6) {
    const size_t bm = (size_t)(b * MM + m);
    float p = 0.f, t1 = 0.f, t2 = 0.f;
#pragma unroll
    for (int i = 0; i < 6; ++i) {
      int s = lane * 6 + i;
      float g = gt[bm * RR + s];
      float a = (g >= 0.5f && s < nr && m < nm) ? g : 0.f;
      float e = aff[bm * RR + s];
      p += a;
      t1 += a * e;
      t2 += (a > 0.f) ? a * __logf(a) : 0.f;
    }
#pragma unroll
    for (int off = 32; off > 0; off >>= 1) {
      p += __shfl_xor(p, off);
      t1 += __shfl_xor(t1, off);
      t2 += __shfl_xor(t2, off);
    }
    if (lane == 0) {
      rsumL[m] = p;
      EmL[m] = (p > 0.f) ? (t1 - t2) / p + __logf(p) : 0.f;
    }
  }
  __syncthreads();
  if (tid == 0) {
    int c = 0;
    for (int m = 0; m < MM; ++m)
      if (rsumL[m] > 0.f) mlistL[c++] = m;
    kcntL = c;
    for (int j = c; j < MM; ++j) mlistL[j] = 0;
  }
  __syncthreads();
  if (chunk == 0 && tid < MM) {
    Em[b * MM + tid] = EmL[tid];
    mlist[b * MM + tid] = mlistL[tid];
    if (tid == 0) kcnt[b] = kcntL;
  }
  const int K = kcntL;

  // ---- staging ----
  for (int h = 0; h < 16; ++h)
    for (int s = tid; s < RR; s += 384)
      h1T[h][s] = h0h1[((size_t)b * RR + s) * 32 + 16 + h];
  for (int i = tid; i < 768; i += 384) {
    int row = i >> 4, h = i & 15;
    h0L[row][h] = h0h1[((size_t)b * RR + r0 + row) * 32 + h];
  }
  for (int j = 0; j < MM; ++j) {
    if (j < K) {
      int m = mlistL[j];
      float inv = 1.f / rsumL[m];
      for (int s = tid; s < RR; s += 384) {
        float g = gt[((size_t)(b * MM + m)) * RR + s];
        RP[j][s] = (g >= 0.5f && s < nr) ? g * inv : 0.f;
      }
    } else {
      for (int s = tid; s < RR; s += 384) RP[j][s] = 0.f;
    }
  }
  float w0[16];
#pragma unroll
  for (int h = 0; h < 16; ++h) w0[h] = trw[h];
  const float tb = trb[0];
  __syncthreads();

  const int r = tid >> 3;        // 0..47
  const int jq = tid & 7;        // 0..7
  const int gr = r0 + r;

  // tran: thread (r,jq) owns interleaved columns s = jq + 8*i
  for (int i = 0; i < 48; ++i) {
    const int s = jq + 8 * i;
    float a = tb;
#pragma unroll
    for (int h = 0; h < 16; ++h)
      a += fmaxf(h0L[r][h] + h1T[h][s], 0.f) * w0[h];
    Tl[r][s] = a;
  }
  __syncthreads();

  // ---- fp8 export: row max over 8 jq lanes (contiguous 48-col slices) ----
  {
    float rmax = -3.0e38f;
    for (int c = 0; c < 48; c += 4) {
      float4 v = *(const float4*)&Tl[r][jq * 48 + c];
      rmax = fmaxf(rmax, fmaxf(fmaxf(v.x, v.y), fmaxf(v.z, v.w)));
    }
    rmax = fmaxf(rmax, __shfl_xor(rmax, 1));
    rmax = fmaxf(rmax, __shfl_xor(rmax, 2));
    rmax = fmaxf(rmax, __shfl_xor(rmax, 4));
    if (jq == 0) expTmax[b * RR + gr] = __expf(rmax);
    unsigned char* obase = expb + ((size_t)b * RR + gr) * RR + jq * 48;
#pragma unroll
    for (int c16 = 0; c16 < 3; ++c16) {
      int w4[4];
#pragma unroll
      for (int ii = 0; ii < 4; ++ii) {
        float4 v = *(const float4*)&Tl[r][jq * 48 + c16 * 16 + ii * 4];
        int pk = __builtin_amdgcn_cvt_pk_fp8_f32(__expf(v.x - rmax),
                                                 __expf(v.y - rmax), 0, false);
        pk = __builtin_amdgcn_cvt_pk_fp8_f32(__expf(v.z - rmax),
                                             __expf(v.w - rmax), pk, true);
        w4[ii] = pk;
      }
      *(int4*)(obase + c16 * 16) = make_int4(w4[0], w4[1], w4[2], w4[3]);
    }
  }

  // ---- bilinear partials: 3 j's per thread ----
  float acc[3] = {0, 0, 0};
  for (int s0 = 0; s0 < RR; s0 += 4) {
    float4 tv = *(const float4*)&Tl[r][s0];
#pragma unroll
    for (int jj = 0; jj < 3; ++jj) {
      const float4 p0 = *(const float4*)&RP[jq * 3 + jj][s0];
      acc[jj] = fmaf(tv.x, p0.x, acc[jj]);
      acc[jj] = fmaf(tv.y, p0.y, acc[jj]);
      acc[jj] = fmaf(tv.z, p0.z, acc[jj]);
      acc[jj] = fmaf(tv.w, p0.w, acc[jj]);
    }
  }
#pragma unroll
  for (int jj = 0; jj < 3; ++jj) {
    const int jp = jq * 3 + jj;
    const int j = jp + 1;
    part[r][j] = (j < K) ? RP[j][gr] * acc[jj] : 0.f;
  }
  __syncthreads();
  if (tid < MM) {
    const int j = tid;
    float s = 0.f;
    if (j >= 1) {
#pragma unroll 4
      for (int rr2 = 0; rr2 < 48; ++rr2) s += part[rr2][j];
    }
    bilinP[(size_t)(b * 8 + chunk) * MM + j] = s;
  }
}

// ---------------- Kernel D: fp8 MFMA scan + fused final reduction -----------
__global__ __launch_bounds__(512, 1) void kD(
    const unsigned char* __restrict__ expb, const float* __restrict__ expTmax,
    const float* __restrict__ aff, const int* __restrict__ nreg,
    const int* __restrict__ mlist, const int* __restrict__ kcnt,
    const float* __restrict__ Em, const float* __restrict__ bilinP,
    const int* __restrict__ nmen, float* __restrict__ result,
    unsigned* __restrict__ cnt, float* __restrict__ out) {
  __shared__ unsigned char eT[RR * EPITCH];    // 153600 B, padded rows
  __shared__ float tf[2][RR];
  __shared__ unsigned int tq[RR / 4];
  __shared__ float wred[2][8];
  __shared__ float fred[8];

  const int b = blockIdx.x;
  const int tid = threadIdx.x;
  const int w = tid >> 6;
  const int lane = tid & 63;
  const int r = lane & 15;
  const int q = lane >> 4;
  const bool act = (r == 0);
  const int nr = nreg[b];

  const int K = kcnt[b];

  // final-reduction tail, shared by both paths (executed by tid 0 at end)
  auto FINISH = [&](float val) {
    __hip_atomic_store(&result[b], val, __ATOMIC_RELEASE,
                       __HIP_MEMORY_SCOPE_AGENT);
    unsigned prev = __hip_atomic_fetch_add(&cnt[0], 1u, __ATOMIC_ACQ_REL,
                                           __HIP_MEMORY_SCOPE_AGENT);
    if (prev == BB - 1) {          // last block: deterministic in-order sum
      float s = 0.f;
      int d = 0;
      for (int bb = 0; bb < BB; ++bb) {
        s += __hip_atomic_load(&result[bb], __ATOMIC_ACQUIRE,
                               __HIP_MEMORY_SCOPE_AGENT);
        d += nmen[bb];
      }
      if (d < 1) d = 1;
      out[0] = s / (float)d;
    }
  };

  if (K == 0) {
    if (tid == 0) FINISH(0.f);
    return;
  }

  {  // stage fp8 tile -> padded LDS rows
    const uint4* src = (const uint4*)(expb + (size_t)b * RR * RR);
#pragma unroll
    for (int j = 0; j < 18; ++j) {
      const int i = tid + j * 512;
      uint4 v = src[i];
      const int row = i / 24;
      const int c = (i - row * 24) * 16;
      *(uint4*)(eT + row * EPITCH + c) = v;
    }
  }
  __syncthreads();

  long long af0[12], af1[12], af2[12];
  {
    const int base = (w * 48 + r) * EPITCH + q * 8;
#pragma unroll
    for (int kt = 0; kt < 12; ++kt) {
      af0[kt] = *(const long long*)(eT + base + kt * 32);
      af1[kt] = *(const long long*)(eT + base + 16 * EPITCH + kt * 32);
      af2[kt] = *(const long long*)(eT + base + 32 * EPITCH + kt * 32);
    }
  }

  float sF4[3][4], eraw4[3][4];
  if (act) {
#pragma unroll
    for (int rt = 0; rt < 3; ++rt) {
      const int rowb = w * 48 + rt * 16 + q * 4;
      *(float4*)sF4[rt] = *(const float4*)&expTmax[b * RR + rowb];
      const int m0 = mlist[b * MM];
      *(float4*)eraw4[rt] =
          *(const float4*)(aff + ((size_t)(b * MM + m0)) * RR + rowb);
    }
  }

  float L = 0.f;

  for (int k = 0; k < K; ++k) {
    const int wpar = (k + 1) & 1;

    float nraw4[3][4] = {{0, 0, 0, 0}, {0, 0, 0, 0}, {0, 0, 0, 0}};
    if (act && k + 1 < K) {
      const int mn = mlist[b * MM + k + 1];
#pragma unroll
      for (int rt = 0; rt < 3; ++rt) {
        const int rowb = w * 48 + rt * 16 + q * 4;
        *(float4*)nraw4[rt] =
            *(const float4*)(aff + ((size_t)(b * MM + mn)) * RR + rowb);
      }
    }

    float tv[3][4] = {{0, 0, 0, 0}, {0, 0, 0, 0}, {0, 0, 0, 0}};
    if (k == 0) {
      if (act) {
#pragma unroll
        for (int rt = 0; rt < 3; ++rt)
#pragma unroll
          for (int i = 0; i < 4; ++i) {
            const int row = w * 48 + rt * 16 + q * 4 + i;
            tv[rt][i] = (row < nr) ? __expf(eraw4[rt][i]) : 0.f;
          }
      }
    } else {
      f32x4v acc0 = {0.f, 0.f, 0.f, 0.f}, acc1 = {0.f, 0.f, 0.f, 0.f},
             acc2 = {0.f, 0.f, 0.f, 0.f};
#pragma unroll
      for (int kt = 0; kt < 12; ++kt) {
        long long bf =
            *(const long long*)((const unsigned char*)tq + kt * 32 + q * 8);
        bf = act ? bf : 0ll;
        acc0 = __builtin_amdgcn_mfma_f32_16x16x32_fp8_fp8(af0[kt], bf, acc0, 0, 0, 0);
        acc1 = __builtin_amdgcn_mfma_f32_16x16x32_fp8_fp8(af1[kt], bf, acc1, 0, 0, 0);
        acc2 = __builtin_amdgcn_mfma_f32_16x16x32_fp8_fp8(af2[kt], bf, acc2, 0, 0, 0);
      }
      if (act) {
#pragma unroll
        for (int i = 0; i < 4; ++i) {
          tv[0][i] = acc0[i] * (__expf(eraw4[0][i]) * sF4[0][i] * 0.00390625f);
          tv[1][i] = acc1[i] * (__expf(eraw4[1][i]) * sF4[1][i] * 0.00390625f);
          tv[2][i] = acc2[i] * (__expf(eraw4[2][i]) * sF4[2][i] * 0.00390625f);
        }
      }
    }

    float lm = 0.f;
    if (act) {
#pragma unroll
      for (int rt = 0; rt < 3; ++rt) {
        const int rowb = w * 48 + rt * 16 + q * 4;
        *(float4*)&tf[wpar][rowb] =
            make_float4(tv[rt][0], tv[rt][1], tv[rt][2], tv[rt][3]);
        lm = fmaxf(lm, fmaxf(fmaxf(tv[rt][0], tv[rt][1]),
                             fmaxf(tv[rt][2], tv[rt][3])));
      }
#pragma unroll
      for (int rt = 0; rt < 3; ++rt)
#pragma unroll
        for (int i = 0; i < 4; ++i) eraw4[rt][i] = nraw4[rt][i];
    }
    lm = fmaxf(lm, __shfl_xor(lm, 16));
    lm = fmaxf(lm, __shfl_xor(lm, 32));
    if (lane == 0) wred[wpar][w] = lm;
    __syncthreads();                         // barrier 1

    if (k + 1 < K) {
      float4 z0 = *(const float4*)&wred[wpar][0];
      float4 z1 = *(const float4*)&wred[wpar][4];
      float zm = fmaxf(fmaxf(fmaxf(z0.x, z0.y), fmaxf(z0.z, z0.w)),
                       fmaxf(fmaxf(z1.x, z1.y), fmaxf(z1.z, z1.w)));
      L += __logf(zm);
      const float bscale = 256.f / zm;
      if (tid < 96) {
        float4 v = *(const float4*)&tf[wpar][tid * 4];
        int pk = __builtin_amdgcn_cvt_pk_fp8_f32(v.x * bscale, v.y * bscale,
                                                 0, false);
        pk = __builtin_amdgcn_cvt_pk_fp8_f32(v.z * bscale, v.w * bscale,
                                             pk, true);
        tq[tid] = (unsigned)pk;
      }
      __syncthreads();                       // barrier 2
    }
  }

  // epilogue: fwd & gold, then fused final reduction
  const int fpar = K & 1;
  float fp = (tid < RR) ? tf[fpar][tid] : 0.f;
#pragma unroll
  for (int off = 32; off > 0; off >>= 1) fp += __shfl_xor(fp, off);
  if (lane == 0) fred[w] = fp;
  __syncthreads();
  if (tid == 0) {
    float fs = 0.f;
#pragma unroll
    for (int i = 0; i < 8; ++i) fs += fred[i];
    const float fwd = L + __logf(fmaxf(fs, 1e-37f));
    float gold = Em[b * MM + mlist[b * MM + 0]];
    for (int j = 1; j < K; ++j) {
      float bil = 0.f;
#pragma unroll
      for (int c = 0; c < 8; ++c) bil += bilinP[(size_t)(b * 8 + c) * MM + j];
      gold += bil + Em[b * MM + mlist[b * MM + j]];
    }
    FINISH(fwd - gold);
  }
}

extern "C" void kernel_launch(void* const* d_in, const int* in_sizes, int n_in,
                              void* d_out, int out_size, void* d_ws, size_t ws_size,
                              hipStream_t stream) {
  const float* region = (const float*)d_in[0];
  const float* aff    = (const float*)d_in[1];
  const float* gt     = (const float*)d_in[2];
  const int*   nmen   = (const int*)d_in[3];
  const int*   nreg   = (const int*)d_in[4];
  const float* t0w    = (const float*)d_in[5];
  const float* t0b    = (const float*)d_in[6];
  const float* t1w    = (const float*)d_in[7];
  const float* t1b    = (const float*)d_in[8];
  const float* trw    = (const float*)d_in[9];
  const float* trb    = (const float*)d_in[10];
  float* out = (float*)d_out;
  char* ws = (char*)d_ws;

  size_t off = 0;
  auto alloc = [&](size_t bytes) {
    void* p = ws + off;
    off += (bytes + 255) & ~(size_t)255;
    return p;
  };
  float*         h0h1    = (float*)alloc((size_t)BB * RR * 32 * 4);       // 1.57 MB
  unsigned char* expb    = (unsigned char*)alloc((size_t)BB * RR * RR);   // 4.72 MB
  float*         expTmax = (float*)alloc((size_t)BB * RR * 4);
  int*           mlist   = (int*)alloc((size_t)BB * MM * 4);
  int*           kcnt    = (int*)alloc((size_t)BB * 4);
  float*         Em      = (float*)alloc((size_t)BB * MM * 4);
  float*         bilinP  = (float*)alloc((size_t)BB * 8 * MM * 4);
  float*         result  = (float*)alloc((size_t)BB * 4);
  unsigned*      cnt     = (unsigned*)alloc(256);

  hipMemsetAsync(cnt, 0, 4, stream);
  kA<<<(BB * RR) / 32, 256, 0, stream>>>(region, t0w, t0b, t1w, t1b, h0h1);
  kYT<<<256, 384, 0, stream>>>(h0h1, trw, trb, gt, aff, nmen, nreg,
                               mlist, kcnt, Em, bilinP, expb, expTmax);
  kD<<<BB, 512, 0, stream>>>(expb, expTmax, aff, nreg, mlist, kcnt, Em,
                             bilinP, nmen, result, cnt, out);
}

// Round 23
// 105.677 us; speedup vs baseline: 1.0829x; 1.0829x over previous
//
#include <hip/hip_runtime.h>

#define NEGV (-100000000.0f)
typedef __attribute__((ext_vector_type(2))) float f32x2;
typedef __attribute__((ext_vector_type(8))) short bf16x8;
typedef __attribute__((ext_vector_type(4))) float f32x4v;

constexpr int BB = 32, MM = 24, RR = 384, DD = 2048;
constexpr int EPITCH = 400;   // eT row pitch (bytes): 100 dwords = 4 mod 32 banks

// pack two f32 -> two bf16 (round half-up)
static __device__ __forceinline__ unsigned pk2bf(float a, float b) {
  unsigned au = __float_as_uint(a) + 0x8000u;
  unsigned bu = __float_as_uint(b) + 0x8000u;
  return (au >> 16) | (bu & 0xffff0000u);
}

// ---------------- Kernel A: cast+MFMA GEMM, 256 thr, depth-3 reg pipeline ---
__global__ __launch_bounds__(256) void kA(const float* __restrict__ region,
    const float* __restrict__ t0w, const float* __restrict__ t0b,
    const float* __restrict__ t1w, const float* __restrict__ t1b,
    float* __restrict__ h0h1) {
  __shared__ unsigned short Abuf[2][32 * 128];
  __shared__ unsigned short Bbuf[2][32 * 128];
  const int tid = threadIdx.x;
  const int row0 = blockIdx.x * 32;

  const int srow = tid >> 3;
  const int sq = tid & 7;
  const float* aSrc = region + (size_t)(row0 + srow) * DD + sq * 16;
  const float* bSrc = ((srow < 16) ? (t0w + (size_t)srow * DD)
                                   : (t1w + (size_t)(srow - 16) * DD)) + sq * 16;

  auto LOADS = [&](float4* s, int t) {
    const int d0 = t * 128;
#pragma unroll
    for (int i = 0; i < 4; ++i) s[i] = *(const float4*)(aSrc + d0 + i * 4);
#pragma unroll
    for (int i = 0; i < 4; ++i) s[4 + i] = *(const float4*)(bSrc + d0 + i * 4);
  };
  const int wbase = srow * 256 + sq * 32;
  const int wxor = (srow & 7) << 4;
  auto WRITES = [&](const float4* s, int buf) {
    unsigned char* Ab = (unsigned char*)&Abuf[buf][0];
    unsigned char* Bb = (unsigned char*)&Bbuf[buf][0];
#pragma unroll
    for (int i = 0; i < 2; ++i) {
      float4 x = s[i * 2], y = s[i * 2 + 1];
      uint4 pk;
      pk.x = pk2bf(x.x, x.y); pk.y = pk2bf(x.z, x.w);
      pk.z = pk2bf(y.x, y.y); pk.w = pk2bf(y.z, y.w);
      *(uint4*)(Ab + ((wbase + i * 16) ^ wxor)) = pk;
      float4 u = s[4 + i * 2], v = s[4 + i * 2 + 1];
      uint4 qk;
      qk.x = pk2bf(u.x, u.y); qk.y = pk2bf(u.z, u.w);
      qk.z = pk2bf(v.x, v.y); qk.w = pk2bf(v.z, v.w);
      *(uint4*)(Bb + ((wbase + i * 16) ^ wxor)) = qk;
    }
  };

  const int w = tid >> 6;
  const int rt = w & 1;
  const int ht = w >> 1;
  const int lane = tid & 63;
  const int arow = rt * 16 + (lane & 15);
  const int bh = lane & 15;
  const int brow = ht * 16 + bh;
  const int koff = (lane >> 4) * 8;
  const int axor = (arow & 7) << 4;
  const int bxor = (brow & 7) << 4;

  f32x4v acc = {0.f, 0.f, 0.f, 0.f};
  auto MFMAT = [&](int buf) {
    const unsigned char* Ab = (const unsigned char*)&Abuf[buf][0];
    const unsigned char* Bb = (const unsigned char*)&Bbuf[buf][0];
#pragma unroll
    for (int kk = 0; kk < 4; ++kk) {
      const int kb = (kk * 32 + koff) * 2;
      bf16x8 av = *(const bf16x8*)(Ab + ((arow * 256 + kb) ^ axor));
      bf16x8 bv = *(const bf16x8*)(Bb + ((brow * 256 + kb) ^ bxor));
      acc = __builtin_amdgcn_mfma_f32_16x16x32_bf16(av, bv, acc, 0, 0, 0);
    }
  };

  float4 sA[8], sB[8], sC[8];
  LOADS(sA, 0);
  WRITES(sA, 0);
  LOADS(sB, 1);
  LOADS(sC, 2);
  for (int t = 0; t < 16; t += 3) {
    __syncthreads();
    if (t + 1 < 16) WRITES(sB, (t + 1) & 1);
    if (t + 3 < 16) LOADS(sA, t + 3);
    MFMAT(t & 1);
    if (t + 1 < 16) {
      __syncthreads();
      if (t + 2 < 16) WRITES(sC, (t + 2) & 1);
      if (t + 4 < 16) LOADS(sB, t + 4);
      MFMAT((t + 1) & 1);
    }
    if (t + 2 < 16) {
      __syncthreads();
      if (t + 3 < 16) WRITES(sA, (t + 3) & 1);
      if (t + 5 < 16) LOADS(sC, t + 5);
      MFMAT(t & 1);
    }
  }

  const float bias = (ht == 0) ? t0b[bh] : t1b[bh];
#pragma unroll
  for (int i = 0; i < 4; ++i) {
    const int rg = row0 + rt * 16 + (lane >> 4) * 4 + i;
    h0h1[(size_t)rg * 32 + ht * 16 + bh] = acc[i] + bias;
  }
}

// ---------------- Kernel YT: 384 thr; interleaved tran-write columns --------
// grid 256 = (b x 8 chunks of 48 rows). thread = (r 0..47, jq 0..7).
__global__ __launch_bounds__(384) void kYT(const float* __restrict__ h0h1,
    const float* __restrict__ trw, const float* __restrict__ trb,
    const float* __restrict__ gt, const float* __restrict__ aff,
    const int* __restrict__ nmen, const int* __restrict__ nreg,
    int* __restrict__ mlist, int* __restrict__ kcnt, float* __restrict__ Em,
    float* __restrict__ bilinP, unsigned char* __restrict__ expb,
    float* __restrict__ expTmax) {
  __shared__ float h1T[16][388];
  __shared__ float h0L[48][16];
  __shared__ float Tl[48][388];
  __shared__ float RP[MM][392];
  __shared__ float part[48][26];
  __shared__ float rsumL[MM], EmL[MM];
  __shared__ int mlistL[MM];
  __shared__ int kcntL;
  const int b = blockIdx.x & 31;
  const int chunk = blockIdx.x >> 5;
  const int r0 = chunk * 48;
  const int tid = threadIdx.x;
  const int lane = tid & 63;
  const int wv = tid >> 6;
  const int nm = nmen[b], nr = nreg[b];

  // ---- kCM prologue on 6 waves ----
  for (int m = wv; m < MM; m += 6) {
    const size_t bm = (size_t)(b * MM + m);
    float p = 0.f, t1 = 0.f, t2 = 0.f;
#pragma unroll
    for (int i = 0; i < 6; ++i) {
      int s = lane * 6 + i;
      float g = gt[bm * RR + s];
      float a = (g >= 0.5f && s < nr && m < nm) ? g : 0.f;
      float e = aff[bm * RR + s];
      p += a;
      t1 += a * e;
      t2 += (a > 0.f) ? a * __logf(a) : 0.f;
    }
#pragma unroll
    for (int off = 32; off > 0; off >>= 1) {
      p += __shfl_xor(p, off);
      t1 += __shfl_xor(t1, off);
      t2 += __shfl_xor(t2, off);
    }
    if (lane == 0) {
      rsumL[m] = p;
      EmL[m] = (p > 0.f) ? (t1 - t2) / p + __logf(p) : 0.f;
    }
  }
  __syncthreads();
  if (tid == 0) {
    int c = 0;
    for (int m = 0; m < MM; ++m)
      if (rsumL[m] > 0.f) mlistL[c++] = m;
    kcntL = c;
    for (int j = c; j < MM; ++j) mlistL[j] = 0;
  }
  __syncthreads();
  if (chunk == 0 && tid < MM) {
    Em[b * MM + tid] = EmL[tid];
    mlist[b * MM + tid] = mlistL[tid];
    if (tid == 0) kcnt[b] = kcntL;
  }
  const int K = kcntL;

  // ---- staging ----
  for (int h = 0; h < 16; ++h)
    for (int s = tid; s < RR; s += 384)
      h1T[h][s] = h0h1[((size_t)b * RR + s) * 32 + 16 + h];
  for (int i = tid; i < 768; i += 384) {
    int row = i >> 4, h = i & 15;
    h0L[row][h] = h0h1[((size_t)b * RR + r0 + row) * 32 + h];
  }
  for (int j = 0; j < MM; ++j) {
    if (j < K) {
      int m = mlistL[j];
      float inv = 1.f / rsumL[m];
      for (int s = tid; s < RR; s += 384) {
        float g = gt[((size_t)(b * MM + m)) * RR + s];
        RP[j][s] = (g >= 0.5f && s < nr) ? g * inv : 0.f;
      }
    } else {
      for (int s = tid; s < RR; s += 384) RP[j][s] = 0.f;
    }
  }
  float w0[16];
#pragma unroll
  for (int h = 0; h < 16; ++h) w0[h] = trw[h];
  const float tb = trb[0];
  __syncthreads();

  const int r = tid >> 3;        // 0..47
  const int jq = tid & 7;        // 0..7
  const int gr = r0 + r;

  // tran: thread (r,jq) owns interleaved columns s = jq + 8*i
  for (int i = 0; i < 48; ++i) {
    const int s = jq + 8 * i;
    float a = tb;
#pragma unroll
    for (int h = 0; h < 16; ++h)
      a += fmaxf(h0L[r][h] + h1T[h][s], 0.f) * w0[h];
    Tl[r][s] = a;
  }
  __syncthreads();

  // ---- fp8 export: row max over 8 jq lanes (contiguous 48-col slices) ----
  {
    float rmax = -3.0e38f;
    for (int c = 0; c < 48; c += 4) {
      float4 v = *(const float4*)&Tl[r][jq * 48 + c];
      rmax = fmaxf(rmax, fmaxf(fmaxf(v.x, v.y), fmaxf(v.z, v.w)));
    }
    rmax = fmaxf(rmax, __shfl_xor(rmax, 1));
    rmax = fmaxf(rmax, __shfl_xor(rmax, 2));
    rmax = fmaxf(rmax, __shfl_xor(rmax, 4));
    if (jq == 0) expTmax[b * RR + gr] = __expf(rmax);
    unsigned char* obase = expb + ((size_t)b * RR + gr) * RR + jq * 48;
#pragma unroll
    for (int c16 = 0; c16 < 3; ++c16) {
      int w4[4];
#pragma unroll
      for (int ii = 0; ii < 4; ++ii) {
        float4 v = *(const float4*)&Tl[r][jq * 48 + c16 * 16 + ii * 4];
        int pk = __builtin_amdgcn_cvt_pk_fp8_f32(__expf(v.x - rmax),
                                                 __expf(v.y - rmax), 0, false);
        pk = __builtin_amdgcn_cvt_pk_fp8_f32(__expf(v.z - rmax),
                                             __expf(v.w - rmax), pk, true);
        w4[ii] = pk;
      }
      *(int4*)(obase + c16 * 16) = make_int4(w4[0], w4[1], w4[2], w4[3]);
    }
  }

  // ---- bilinear partials: 3 j's per thread ----
  float acc[3] = {0, 0, 0};
  for (int s0 = 0; s0 < RR; s0 += 4) {
    float4 tv = *(const float4*)&Tl[r][s0];
#pragma unroll
    for (int jj = 0; jj < 3; ++jj) {
      const float4 p0 = *(const float4*)&RP[jq * 3 + jj][s0];
      acc[jj] = fmaf(tv.x, p0.x, acc[jj]);
      acc[jj] = fmaf(tv.y, p0.y, acc[jj]);
      acc[jj] = fmaf(tv.z, p0.z, acc[jj]);
      acc[jj] = fmaf(tv.w, p0.w, acc[jj]);
    }
  }
#pragma unroll
  for (int jj = 0; jj < 3; ++jj) {
    const int jp = jq * 3 + jj;
    const int j = jp + 1;
    part[r][j] = (j < K) ? RP[j][gr] * acc[jj] : 0.f;
  }
  __syncthreads();
  if (tid < MM) {
    const int j = tid;
    float s = 0.f;
    if (j >= 1) {
#pragma unroll 4
      for (int rr2 = 0; rr2 < 48; ++rr2) s += part[rr2][j];
    }
    bilinP[(size_t)(b * 8 + chunk) * MM + j] = s;
  }
}

// ---------------- Kernel D: fp8 MFMA scan, A-frags hoisted to registers -----
__global__ __launch_bounds__(512, 1) void kD(
    const unsigned char* __restrict__ expb, const float* __restrict__ expTmax,
    const float* __restrict__ aff, const int* __restrict__ nreg,
    const int* __restrict__ mlist, const int* __restrict__ kcnt,
    const float* __restrict__ Em, const float* __restrict__ bilinP,
    float* __restrict__ result) {
  __shared__ unsigned char eT[RR * EPITCH];    // 153600 B, padded rows
  __shared__ float tf[2][RR];
  __shared__ unsigned int tq[RR / 4];
  __shared__ float wred[2][8];
  __shared__ float fred[8];

  const int b = blockIdx.x;
  const int tid = threadIdx.x;
  const int w = tid >> 6;
  const int lane = tid & 63;
  const int r = lane & 15;
  const int q = lane >> 4;
  const bool act = (r == 0);
  const int nr = nreg[b];

  const int K = kcnt[b];
  if (K == 0) {
    if (tid == 0) result[b] = 0.f;
    return;
  }

  {  // stage fp8 tile -> padded LDS rows
    const uint4* src = (const uint4*)(expb + (size_t)b * RR * RR);
#pragma unroll
    for (int j = 0; j < 18; ++j) {
      const int i = tid + j * 512;
      uint4 v = src[i];
      const int row = i / 24;
      const int c = (i - row * 24) * 16;
      *(uint4*)(eT + row * EPITCH + c) = v;
    }
  }
  __syncthreads();

  long long af0[12], af1[12], af2[12];
  {
    const int base = (w * 48 + r) * EPITCH + q * 8;
#pragma unroll
    for (int kt = 0; kt < 12; ++kt) {
      af0[kt] = *(const long long*)(eT + base + kt * 32);
      af1[kt] = *(const long long*)(eT + base + 16 * EPITCH + kt * 32);
      af2[kt] = *(const long long*)(eT + base + 32 * EPITCH + kt * 32);
    }
  }

  float sF4[3][4], eraw4[3][4];
  if (act) {
#pragma unroll
    for (int rt = 0; rt < 3; ++rt) {
      const int rowb = w * 48 + rt * 16 + q * 4;
      *(float4*)sF4[rt] = *(const float4*)&expTmax[b * RR + rowb];
      const int m0 = mlist[b * MM];
      *(float4*)eraw4[rt] =
          *(const float4*)(aff + ((size_t)(b * MM + m0)) * RR + rowb);
    }
  }

  float L = 0.f;

  for (int k = 0; k < K; ++k) {
    const int wpar = (k + 1) & 1;

    float nraw4[3][4] = {{0, 0, 0, 0}, {0, 0, 0, 0}, {0, 0, 0, 0}};
    if (act && k + 1 < K) {
      const int mn = mlist[b * MM + k + 1];
#pragma unroll
      for (int rt = 0; rt < 3; ++rt) {
        const int rowb = w * 48 + rt * 16 + q * 4;
        *(float4*)nraw4[rt] =
            *(const float4*)(aff + ((size_t)(b * MM + mn)) * RR + rowb);
      }
    }

    float tv[3][4] = {{0, 0, 0, 0}, {0, 0, 0, 0}, {0, 0, 0, 0}};
    if (k == 0) {
      if (act) {
#pragma unroll
        for (int rt = 0; rt < 3; ++rt)
#pragma unroll
          for (int i = 0; i < 4; ++i) {
            const int row = w * 48 + rt * 16 + q * 4 + i;
            tv[rt][i] = (row < nr) ? __expf(eraw4[rt][i]) : 0.f;
          }
      }
    } else {
      f32x4v acc0 = {0.f, 0.f, 0.f, 0.f}, acc1 = {0.f, 0.f, 0.f, 0.f},
             acc2 = {0.f, 0.f, 0.f, 0.f};
#pragma unroll
      for (int kt = 0; kt < 12; ++kt) {
        long long bf =
            *(const long long*)((const unsigned char*)tq + kt * 32 + q * 8);
        bf = act ? bf : 0ll;   // only column 0 carries B
        acc0 = __builtin_amdgcn_mfma_f32_16x16x32_fp8_fp8(af0[kt], bf, acc0, 0, 0, 0);
        acc1 = __builtin_amdgcn_mfma_f32_16x16x32_fp8_fp8(af1[kt], bf, acc1, 0, 0, 0);
        acc2 = __builtin_amdgcn_mfma_f32_16x16x32_fp8_fp8(af2[kt], bf, acc2, 0, 0, 0);
      }
      if (act) {
#pragma unroll
        for (int i = 0; i < 4; ++i) {
          tv[0][i] = acc0[i] * (__expf(eraw4[0][i]) * sF4[0][i] * 0.00390625f);
          tv[1][i] = acc1[i] * (__expf(eraw4[1][i]) * sF4[1][i] * 0.00390625f);
          tv[2][i] = acc2[i] * (__expf(eraw4[2][i]) * sF4[2][i] * 0.00390625f);
        }
      }
    }

    float lm = 0.f;
    if (act) {
#pragma unroll
      for (int rt = 0; rt < 3; ++rt) {
        const int rowb = w * 48 + rt * 16 + q * 4;
        *(float4*)&tf[wpar][rowb] =
            make_float4(tv[rt][0], tv[rt][1], tv[rt][2], tv[rt][3]);
        lm = fmaxf(lm, fmaxf(fmaxf(tv[rt][0], tv[rt][1]),
                             fmaxf(tv[rt][2], tv[rt][3])));
      }
#pragma unroll
      for (int rt = 0; rt < 3; ++rt)
#pragma unroll
        for (int i = 0; i < 4; ++i) eraw4[rt][i] = nraw4[rt][i];
    }
    lm = fmaxf(lm, __shfl_xor(lm, 16));
    lm = fmaxf(lm, __shfl_xor(lm, 32));
    if (lane == 0) wred[wpar][w] = lm;
    __syncthreads();                         // barrier 1

    if (k + 1 < K) {
      float4 z0 = *(const float4*)&wred[wpar][0];
      float4 z1 = *(const float4*)&wred[wpar][4];
      float zm = fmaxf(fmaxf(fmaxf(z0.x, z0.y), fmaxf(z0.z, z0.w)),
                       fmaxf(fmaxf(z1.x, z1.y), fmaxf(z1.z, z1.w)));
      L += __logf(zm);
      const float bscale = 256.f / zm;
      if (tid < 96) {
        float4 v = *(const float4*)&tf[wpar][tid * 4];
        int pk = __builtin_amdgcn_cvt_pk_fp8_f32(v.x * bscale, v.y * bscale,
                                                 0, false);
        pk = __builtin_amdgcn_cvt_pk_fp8_f32(v.z * bscale, v.w * bscale,
                                             pk, true);
        tq[tid] = (unsigned)pk;
      }
      __syncthreads();                       // barrier 2
    }
  }

  // epilogue
  const int fpar = K & 1;
  float fp = (tid < RR) ? tf[fpar][tid] : 0.f;
#pragma unroll
  for (int off = 32; off > 0; off >>= 1) fp += __shfl_xor(fp, off);
  if (lane == 0) fred[w] = fp;
  __syncthreads();
  if (tid == 0) {
    float fs = 0.f;
#pragma unroll
    for (int i = 0; i < 8; ++i) fs += fred[i];
    const float fwd = L + __logf(fmaxf(fs, 1e-37f));
    float gold = Em[b * MM + mlist[b * MM + 0]];
    for (int j = 1; j < K; ++j) {
      float bil = 0.f;
#pragma unroll
      for (int c = 0; c < 8; ++c) bil += bilinP[(size_t)(b * 8 + c) * MM + j];
      gold += bil + Em[b * MM + mlist[b * MM + j]];
    }
    result[b] = fwd - gold;
  }
}

// ---------------- Kernel E: final deterministic reduction ----------
__global__ void kE(const float* __restrict__ result, const int* __restrict__ nmen,
                   float* __restrict__ out) {
  if (threadIdx.x == 0 && blockIdx.x == 0) {
    float s = 0.f;
    int d = 0;
    for (int b = 0; b < 32; ++b) { s += result[b]; d += nmen[b]; }
    if (d < 1) d = 1;
    out[0] = s / (float)d;
  }
}

extern "C" void kernel_launch(void* const* d_in, const int* in_sizes, int n_in,
                              void* d_out, int out_size, void* d_ws, size_t ws_size,
                              hipStream_t stream) {
  const float* region = (const float*)d_in[0];
  const float* aff    = (const float*)d_in[1];
  const float* gt     = (const float*)d_in[2];
  const int*   nmen   = (const int*)d_in[3];
  const int*   nreg   = (const int*)d_in[4];
  const float* t0w    = (const float*)d_in[5];
  const float* t0b    = (const float*)d_in[6];
  const float* t1w    = (const float*)d_in[7];
  const float* t1b    = (const float*)d_in[8];
  const float* trw    = (const float*)d_in[9];
  const float* trb    = (const float*)d_in[10];
  float* out = (float*)d_out;
  char* ws = (char*)d_ws;

  size_t off = 0;
  auto alloc = [&](size_t bytes) {
    void* p = ws + off;
    off += (bytes + 255) & ~(size_t)255;
    return p;
  };
  float*         h0h1    = (float*)alloc((size_t)BB * RR * 32 * 4);       // 1.57 MB
  unsigned char* expb    = (unsigned char*)alloc((size_t)BB * RR * RR);   // 4.72 MB
  float*         expTmax = (float*)alloc((size_t)BB * RR * 4);
  int*           mlist   = (int*)alloc((size_t)BB * MM * 4);
  int*           kcnt    = (int*)alloc((size_t)BB * 4);
  float*         Em      = (float*)alloc((size_t)BB * MM * 4);
  float*         bilinP  = (float*)alloc((size_t)BB * 8 * MM * 4);
  float*         result  = (float*)alloc((size_t)BB * 4);

  kA<<<(BB * RR) / 32, 256, 0, stream>>>(region, t0w, t0b, t1w, t1b, h0h1);
  kYT<<<256, 384, 0, stream>>>(h0h1, trw, trb, gt, aff, nmen, nreg,
                               mlist, kcnt, Em, bilinP, expb, expTmax);
  kD<<<BB, 512, 0, stream>>>(expb, expTmax, aff, nreg, mlist, kcnt, Em,
                             bilinP, result);
  kE<<<1, 64, 0, stream>>>(result, nmen, out);
}